// Round 4
// baseline (146.786 us; speedup 1.0000x reference)
//
#include <hip/hip_runtime.h>

typedef unsigned short ushort_t;
typedef ushort_t u16x8 __attribute__((ext_vector_type(8)));
typedef __bf16 bf16x8 __attribute__((ext_vector_type(8)));
typedef float f32x4 __attribute__((ext_vector_type(4)));

#define DET 736
#define NPAD 768
#define NT 23   // K-steps: 736 / 32

__device__ __forceinline__ ushort_t f2bf(float f) {
    unsigned u = __builtin_bit_cast(unsigned, f);
    u += 0x7FFFu + ((u >> 16) & 1u);
    return (ushort_t)(u >> 16);
}

// async global->LDS, 16B per lane. Dest must be wave-uniform base + lane*16.
__device__ __forceinline__ void gload16(const void* g, void* l) {
    __builtin_amdgcn_global_load_lds(
        (const __attribute__((address_space(1))) unsigned int*)g,
        (__attribute__((address_space(3))) unsigned int*)l,
        16, 0, 0);
}

// Bt[n][k] = w[k] * f[k - n + 735]   (cosine pre-weight folded into the filter
// matrix: OUT = (X . w) * W  ==  X * (diag(w) W)).  Rows n>=736 are zero pad.
__global__ void prep_bt(const float* __restrict__ filt, ushort_t* __restrict__ Bt) {
    int idx = blockIdx.x * blockDim.x + threadIdx.x;
    if (idx >= NPAD * DET) return;
    int n = idx / DET;
    int k = idx - n * DET;
    float w = 0.05f * cosf(((float)k - 367.5f) * 0.001f);
    float v = (n < DET) ? filt[k - n + (DET - 1)] * w : 0.0f;  // index in [0,1471)
    Bt[idx] = f2bf(v);
}

// OUT[M x 736] = sino[M x 736] * W'[736 x 736]
// Structure (round 4):
//  - A: raw fp32 sinogram staged via gload_lds into double-buffered LDS
//    (16 KB/tile), XOR-swizzled via pre-swizzled GLOBAL source (rule #21:
//    both-sides swizzle; fp32 rows are 128B -> unswizzled = 16-way conflict).
//    Stage t+1 issues at top of compute t; end-of-iter barrier drain overlaps
//    the MFMAs. bf16 cvt happens in-register at fragment read (RNE == f2bf).
//  - B: NO LDS. 188 KB/column-block Toeplitz is L2-resident; fragments load
//    global->VGPR (16B/lane contiguous), reg-double-buffered one iter ahead.
__global__ __launch_bounds__(256, 3) void gemm_fused(
    const float* __restrict__ A,      // M x DET fp32 sinogram
    const ushort_t* __restrict__ Bt,  // NPAD x DET bf16 bits
    float* __restrict__ C, int M)
{
    __shared__ float As[2][128 * 32];   // 2 x 16 KB

    const int tid  = threadIdx.x;
    const int lane = tid & 63;
    const int warp = tid >> 6;   // 0..3
    const int wm   = warp & 1;   // 2x2 wave grid
    const int wn   = warp >> 1;
    const int quad = lane >> 4;  // 0..3
    const int l16  = lane & 15;

    const size_t row_a0 = (size_t)blockIdx.x * 128;
    const int    row_b0 = blockIdx.y * 128;

    f32x4 acc[4][4];
#pragma unroll
    for (int i = 0; i < 4; ++i)
#pragma unroll
        for (int jx = 0; jx < 4; ++jx)
            acc[i][jx] = (f32x4){0.f, 0.f, 0.f, 0.f};

    // A staging: tile = 128 rows x 32 fp32 = 1024 chunks of 16B; 4 chunks/thread.
    // chunk c: row=c>>3, part=c&7; LDS holds global chunk (row, part^(row&7)).
    const float* gsrc[4];
    int          cdst[4];
#pragma unroll
    for (int i = 0; i < 4; ++i) {
        int c    = tid + i * 256;
        int row  = c >> 3;
        int part = c & 7;
        int sp   = part ^ (row & 7);
        gsrc[i]  = A + (row_a0 + row) * DET + sp * 4;   // + k0 (elements)
        cdst[i]  = c * 4;                               // float index in As
    }

    // B fragment pointers: lane reads 8 contiguous bf16 of one output column.
    const ushort_t* gBp[4];
#pragma unroll
    for (int ni = 0; ni < 4; ++ni)
        gBp[ni] = Bt + (size_t)(row_b0 + wn * 64 + ni * 16 + l16) * DET + quad * 8;

    // fragment-read swizzle offsets (row&7 == l16&7 since wm*64, mi*16 are mult of 8)
    const int r7   = l16 & 7;
    const int o_lo = ((quad * 2)     ^ r7) * 4;   // float offset of k quad*8..+3
    const int o_hi = ((quad * 2 + 1) ^ r7) * 4;   // float offset of k quad*8+4..+7

    // prologue: stage A tile 0 into buf 0; load B frags for tile 0
#pragma unroll
    for (int i = 0; i < 4; ++i)
        gload16(gsrc[i], &As[0][cdst[i]]);
    u16x8 bcur[4];
#pragma unroll
    for (int ni = 0; ni < 4; ++ni)
        bcur[ni] = *(const u16x8*)(gBp[ni]);
    __syncthreads();   // drains vmcnt(0): A tile 0 + B frags 0 ready

    for (int t = 0; t < NT; ++t) {
        const int cur = t & 1;
        const int kn  = (t + 1 < NT) ? (t + 1) * 32 : 0;   // clamped prefetch

        // issue next A stage (async DMA into other buffer) + next B frags;
        // their latency hides under this iter's ds_read+cvt+MFMA.
#pragma unroll
        for (int i = 0; i < 4; ++i)
            gload16(gsrc[i] + kn, &As[cur ^ 1][cdst[i]]);
        u16x8 bnext[4];
#pragma unroll
        for (int ni = 0; ni < 4; ++ni)
            bnext[ni] = *(const u16x8*)(gBp[ni] + kn);

        // A fragments: swizzled ds_read (fp32) + cvt to bf16 in-register
        bf16x8 af[4];
#pragma unroll
        for (int mi = 0; mi < 4; ++mi) {
            const int row = wm * 64 + mi * 16 + l16;
            f32x4 lo = *(const f32x4*)(&As[cur][row * 32 + o_lo]);
            f32x4 hi = *(const f32x4*)(&As[cur][row * 32 + o_hi]);
            bf16x8 v;
#pragma unroll
            for (int e = 0; e < 4; ++e) {
                v[e]     = (__bf16)lo[e];
                v[e + 4] = (__bf16)hi[e];
            }
            af[mi] = v;
        }

#pragma unroll
        for (int mi = 0; mi < 4; ++mi)
#pragma unroll
            for (int ni = 0; ni < 4; ++ni)
                acc[mi][ni] = __builtin_amdgcn_mfma_f32_16x16x32_bf16(
                    af[mi],
                    __builtin_bit_cast(bf16x8, bcur[ni]),
                    acc[mi][ni], 0, 0, 0);

        __syncthreads();   // drains vmcnt(0): A[t+1] in LDS, B[t+1] in regs
#pragma unroll
        for (int ni = 0; ni < 4; ++ni)
            bcur[ni] = bnext[ni];
    }

    // epilogue: C/D layout col=lane&15, row=quad*4+reg [verified mapping]
#pragma unroll
    for (int mi = 0; mi < 4; ++mi) {
#pragma unroll
        for (int ni = 0; ni < 4; ++ni) {
            int colg = row_b0 + wn * 64 + ni * 16 + l16;
            if (colg < DET) {
#pragma unroll
                for (int r = 0; r < 4; ++r) {
                    size_t rowg = row_a0 + wm * 64 + mi * 16 + quad * 4 + r;
                    C[rowg * DET + colg] = acc[mi][ni][r];
                }
            }
        }
    }
}

extern "C" void kernel_launch(void* const* d_in, const int* in_sizes, int n_in,
                              void* d_out, int out_size, void* d_ws, size_t ws_size,
                              hipStream_t stream) {
    const float* sino = (const float*)d_in[0];
    const float* filt = (const float*)d_in[1];
    int total = in_sizes[0];     // 16*1*1152*736 = 13,565,952
    int M = total / DET;         // 18432

    ushort_t* Btb = (ushort_t*)d_ws;   // 768*736*2 = 1.08 MB
    float* out = (float*)d_out;

    prep_bt<<<(NPAD * DET + 255) / 256, 256, 0, stream>>>(filt, Btb);

    dim3 grid(M / 128, NPAD / 128);  // 144 x 6
    gemm_fused<<<grid, 256, 0, stream>>>(sino, Btb, out, M);
}